// Round 2
// baseline (157.262 us; speedup 1.0000x reference)
//
#include <hip/hip_runtime.h>
#include <math.h>

#define B_TOTAL 16384
#define F_TOTAL 256
#define H1 32
#define H2 16

typedef __attribute__((ext_vector_type(8))) short bf16x8;
typedef __attribute__((ext_vector_type(4))) float floatx4;

union FragU { unsigned int u[4]; bf16x8 v; };

// Split 8 fp32 into trunc-bf16 hi (packed, 4 dwords) + trunc-bf16 lo (packed).
// hi+lo reconstructs x to ~2^-17 rel; mfma(hi,hi)+mfma(hi,lo)+mfma(lo,hi)
// recovers near-fp32 product accuracy.
__device__ __forceinline__ void split_pack8(const float* h,
                                            unsigned int* hi_dw,
                                            unsigned int* lo_dw) {
    unsigned int hb[8];
    unsigned int lb[8];
    #pragma unroll
    for (int j = 0; j < 8; ++j) {
        unsigned int bits = __float_as_uint(h[j]);
        hb[j] = bits & 0xFFFF0000u;
        float hf = __uint_as_float(hb[j]);
        lb[j] = __float_as_uint(h[j] - hf);
    }
    #pragma unroll
    for (int t = 0; t < 4; ++t) {
        // short element 2t = low half of dword t (bf16 of h[2t])
        hi_dw[t] = (hb[2*t] >> 16) | hb[2*t + 1];
        lo_dw[t] = (lb[2*t] >> 16) | (lb[2*t + 1] & 0xFFFF0000u);
    }
}

// Pre-pack W2 [F][H1][H2] fp32 -> B-fragment layout bf16 hi/lo:
// lane l of feature f holds B[k=(l>>4)*8+j][n=l&15], j=0..7 (16 B each).
__global__ __launch_bounds__(64) void nam_pack(
    const float* __restrict__ W2,
    unsigned int* __restrict__ wsHi,
    unsigned int* __restrict__ wsLo)
{
    const int f = blockIdx.x;
    const int lane = threadIdx.x;
    const int n = lane & 15, q = lane >> 4;
    float w[8];
    #pragma unroll
    for (int j = 0; j < 8; ++j)
        w[j] = W2[(size_t)f * (H1 * H2) + (q * 8 + j) * H2 + n];
    unsigned int hi[4], lo[4];
    split_pack8(w, hi, lo);
    uint4* dh = (uint4*)(wsHi + ((size_t)f * 64 + lane) * 4);
    uint4* dl = (uint4*)(wsLo + ((size_t)f * 64 + lane) * 4);
    *dh = make_uint4(hi[0], hi[1], hi[2], hi[3]);
    *dl = make_uint4(lo[0], lo[1], lo[2], lo[3]);
}

// Main: each wave owns one 16-batch tile x nfeat features.
// Layer1 (rank-1) on VALU -> h1 split to bf16 hi/lo A-frag; layer2 via
// 3x mfma_f32_16x16x32_bf16; epilogue (b2, relu, *W3) per C element;
// per-feature contribs accumulate in registers; one cross-lane reduce
// over n (16 lanes) at the end; partial written per feature-group.
template<bool PACKED>
__global__ __launch_bounds__(256, 2) void nam_main(
    const float* __restrict__ x,   // [B, F]
    const float* __restrict__ W1,  // [F, 1, H1]
    const float* __restrict__ b1,  // [F, H1]
    const float* __restrict__ W2,  // [F, H1, H2]
    const float* __restrict__ b2,  // [F, H2]
    const float* __restrict__ W3,  // [F, H2, 1]
    const float* __restrict__ b3,  // [F, 1]
    const uint4* __restrict__ w2hi,
    const uint4* __restrict__ w2lo,
    float* __restrict__ part,      // [ngroups, B]
    int nfeat)
{
    const int lane = threadIdx.x & 63;
    const int wave = threadIdx.x >> 6;
    const int n = lane & 15, q = lane >> 4;
    const int tile = blockIdx.x * 4 + wave;
    const int b0 = tile * 16;
    const int f0 = blockIdx.y * nfeat;

    const float* xp  = x  + (size_t)(b0 + n) * F_TOTAL + f0;
    const float* w1p = W1 + (size_t)f0 * H1 + q * 8;
    const float* b1p = b1 + (size_t)f0 * H1 + q * 8;
    const float* b2p = b2 + (size_t)f0 * H2 + n;
    const float* w3p = W3 + (size_t)f0 * H2 + n;
    const float* b3p = b3 + f0;

    floatx4 acc = {0.f, 0.f, 0.f, 0.f};
    float accb3 = 0.f;

    #pragma unroll 2
    for (int fi = 0; fi < nfeat; ++fi) {
        const float xm = xp[fi];
        const float4 wa = *(const float4*)(w1p + (size_t)fi * H1);
        const float4 wb = *(const float4*)(w1p + (size_t)fi * H1 + 4);
        const float4 ba = *(const float4*)(b1p + (size_t)fi * H1);
        const float4 bb = *(const float4*)(b1p + (size_t)fi * H1 + 4);

        float h[8];
        h[0] = fmaf(xm, wa.x, ba.x); h[1] = fmaf(xm, wa.y, ba.y);
        h[2] = fmaf(xm, wa.z, ba.z); h[3] = fmaf(xm, wa.w, ba.w);
        h[4] = fmaf(xm, wb.x, bb.x); h[5] = fmaf(xm, wb.y, bb.y);
        h[6] = fmaf(xm, wb.z, bb.z); h[7] = fmaf(xm, wb.w, bb.w);
        #pragma unroll
        for (int j = 0; j < 8; ++j) h[j] = h[j] > 0.f ? h[j] : 0.f;

        FragU ahi, alo;
        split_pack8(h, ahi.u, alo.u);

        FragU bhi, blo;
        if (PACKED) {
            uint4 vh = w2hi[(size_t)(f0 + fi) * 64 + lane];
            uint4 vl = w2lo[(size_t)(f0 + fi) * 64 + lane];
            bhi.u[0] = vh.x; bhi.u[1] = vh.y; bhi.u[2] = vh.z; bhi.u[3] = vh.w;
            blo.u[0] = vl.x; blo.u[1] = vl.y; blo.u[2] = vl.z; blo.u[3] = vl.w;
        } else {
            float wv[8];
            #pragma unroll
            for (int j = 0; j < 8; ++j)
                wv[j] = W2[(size_t)(f0 + fi) * (H1 * H2) + (q * 8 + j) * H2 + n];
            split_pack8(wv, bhi.u, blo.u);
        }

        floatx4 c = {0.f, 0.f, 0.f, 0.f};
        c = __builtin_amdgcn_mfma_f32_16x16x32_bf16(alo.v, bhi.v, c, 0, 0, 0);
        c = __builtin_amdgcn_mfma_f32_16x16x32_bf16(ahi.v, blo.v, c, 0, 0, 0);
        c = __builtin_amdgcn_mfma_f32_16x16x32_bf16(ahi.v, bhi.v, c, 0, 0, 0);

        const float b2n = b2p[(size_t)fi * H2];
        const float w3n = w3p[(size_t)fi * H2];
        #pragma unroll
        for (int r = 0; r < 4; ++r) {
            float hh = c[r] + b2n;
            hh = hh > 0.f ? hh : 0.f;
            acc[r] = fmaf(hh, w3n, acc[r]);
        }
        accb3 += b3p[fi];
    }

    // Reduce over the 16 columns (n) within each 16-lane group.
    #pragma unroll
    for (int r = 0; r < 4; ++r) {
        float v = acc[r];
        v += __shfl_xor(v, 1);
        v += __shfl_xor(v, 2);
        v += __shfl_xor(v, 4);
        v += __shfl_xor(v, 8);
        acc[r] = v;
    }
    if (n == 0) {
        // lane (q, n=0) holds batch rows b0 + q*4 + r
        float4 o;
        o.x = acc[0] + accb3;
        o.y = acc[1] + accb3;
        o.z = acc[2] + accb3;
        o.w = acc[3] + accb3;
        *(float4*)(part + (size_t)blockIdx.y * B_TOTAL + b0 + q * 4) = o;
    }
}

__global__ __launch_bounds__(256) void nam_finish(
    const float* __restrict__ part, float* __restrict__ out, int ngroups)
{
    const int b = blockIdx.x * 256 + threadIdx.x;
    float s = 0.f;
    for (int g = 0; g < ngroups; ++g) s += part[(size_t)g * B_TOTAL + b];
    out[b] = 1.0f / (1.0f + expf(-s));
}

extern "C" void kernel_launch(void* const* d_in, const int* in_sizes, int n_in,
                              void* d_out, int out_size, void* d_ws, size_t ws_size,
                              hipStream_t stream) {
    const float* x  = (const float*)d_in[0];
    const float* W1 = (const float*)d_in[1];
    const float* b1 = (const float*)d_in[2];
    const float* W2 = (const float*)d_in[3];
    const float* b2 = (const float*)d_in[4];
    const float* W3 = (const float*)d_in[5];
    const float* b3 = (const float*)d_in[6];
    float* out = (float*)d_out;

    const size_t packBytes = (size_t)F_TOTAL * 64 * 16;  // 256 KB per hi/lo
    const size_t partBytes4 = (size_t)4 * B_TOTAL * sizeof(float);  // 256 KB

    if (ws_size >= 2 * packBytes + partBytes4) {
        unsigned int* wsHi = (unsigned int*)d_ws;
        unsigned int* wsLo = (unsigned int*)((char*)d_ws + packBytes);
        float* partp = (float*)((char*)d_ws + 2 * packBytes);

        nam_pack<<<F_TOTAL, 64, 0, stream>>>(W2, wsHi, wsLo);
        dim3 grid(B_TOTAL / 64, 4);  // 4 waves/block, 64 features/wave
        nam_main<true><<<grid, 256, 0, stream>>>(
            x, W1, b1, W2, b2, W3, b3,
            (const uint4*)wsHi, (const uint4*)wsLo, partp, F_TOTAL / 4);
        nam_finish<<<B_TOTAL / 256, 256, 0, stream>>>(partp, out, 4);
    } else {
        // Fallback: no pre-packed W2; split in-kernel. Partials sized to ws.
        int ngroups = (ws_size >= partBytes4) ? 4 : 1;
        float* partp = (float*)d_ws;
        dim3 grid(B_TOTAL / 64, ngroups);
        nam_main<false><<<grid, 256, 0, stream>>>(
            x, W1, b1, W2, b2, W3, b3,
            nullptr, nullptr, partp, F_TOTAL / ngroups);
        nam_finish<<<B_TOTAL / 256, 256, 0, stream>>>(partp, out, ngroups);
    }
}

// Round 3
// 113.612 us; speedup vs baseline: 1.3842x; 1.3842x over previous
//
#include <hip/hip_runtime.h>
#include <math.h>

#define B_TOTAL 16384
#define F_TOTAL 256
#define H1 32
#define H2 16
#define FCHUNK 16   // features staged in LDS per chunk

typedef __attribute__((ext_vector_type(8))) short bf16x8;
typedef __attribute__((ext_vector_type(4))) float floatx4;

union FragU { unsigned int u[4]; bf16x8 v; };

// Split 8 fp32 into trunc-bf16 hi + bf16(x-hi) lo, packed for MFMA A/B frags.
// v_perm_b32 packs two top-halves in one instruction: 24 VALU total.
__device__ __forceinline__ void split_pack8(const float* h,
                                            unsigned int* hi_dw,
                                            unsigned int* lo_dw) {
    unsigned int b[8];
    #pragma unroll
    for (int j = 0; j < 8; ++j) b[j] = __float_as_uint(h[j]);
    #pragma unroll
    for (int t = 0; t < 4; ++t) {
        unsigned int hd = __builtin_amdgcn_perm(b[2*t+1], b[2*t], 0x07060302u);
        hi_dw[t] = hd;
        float hf0 = __uint_as_float(hd << 16);
        float hf1 = __uint_as_float(hd & 0xFFFF0000u);
        unsigned int l0 = __float_as_uint(h[2*t]   - hf0);
        unsigned int l1 = __float_as_uint(h[2*t+1] - hf1);
        lo_dw[t] = __builtin_amdgcn_perm(l1, l0, 0x07060302u);
    }
}

// Pre-pack W2 [F][H1][H2] fp32 -> B-fragment layout bf16 hi/lo:
// lane l of feature f holds B[k=(l>>4)*8+j][n=l&15], j=0..7 (16 B each).
__global__ __launch_bounds__(64) void nam_pack(
    const float* __restrict__ W2,
    unsigned int* __restrict__ wsHi,
    unsigned int* __restrict__ wsLo)
{
    const int f = blockIdx.x;
    const int lane = threadIdx.x;
    const int n = lane & 15, q = lane >> 4;
    float w[8];
    #pragma unroll
    for (int j = 0; j < 8; ++j)
        w[j] = W2[(size_t)f * (H1 * H2) + (q * 8 + j) * H2 + n];
    unsigned int hi[4], lo[4];
    split_pack8(w, hi, lo);
    uint4* dh = (uint4*)(wsHi + ((size_t)f * 64 + lane) * 4);
    uint4* dl = (uint4*)(wsLo + ((size_t)f * 64 + lane) * 4);
    *dh = make_uint4(hi[0], hi[1], hi[2], hi[3]);
    *dl = make_uint4(lo[0], lo[1], lo[2], lo[3]);
}

// Block = 64 batch rows (4 waves x 16) x nfeat features, staged in
// 16-feature LDS chunks. All per-feature operands come from LDS
// (conflict-free broadcast reads); W2 B-frags stream from global,
// software-pipelined 2 deep.
template<bool PACKED>
__global__ __launch_bounds__(256, 4) void nam_main(
    const float* __restrict__ x,   // [B, F]
    const float* __restrict__ W1,  // [F, 1, H1]
    const float* __restrict__ b1,  // [F, H1]
    const float* __restrict__ W2,  // [F, H1, H2]
    const float* __restrict__ b2,  // [F, H2]
    const float* __restrict__ W3,  // [F, H2, 1]
    const float* __restrict__ b3,  // [F, 1]
    const uint4* __restrict__ w2hi,
    const uint4* __restrict__ w2lo,
    float* __restrict__ part,      // [ngroups, B]
    int nfeat)
{
    __shared__ float xs[FCHUNK][64];    // [fi][row]  4 KB
    __shared__ float w1s[FCHUNK][H1];   // 2 KB
    __shared__ float b1s[FCHUNK][H1];   // 2 KB
    __shared__ float b2s[FCHUNK][H2];   // 1 KB
    __shared__ float w3s[FCHUNK][H2];   // 1 KB
    __shared__ float b3s[FCHUNK];       // 64 B

    const int t = threadIdx.x;
    const int lane = t & 63;
    const int wave = t >> 6;
    const int n = lane & 15, q = lane >> 4;
    const int b0 = blockIdx.x * 64;
    const int f0 = blockIdx.y * nfeat;

    floatx4 acc = {0.f, 0.f, 0.f, 0.f};
    float accb3 = 0.f;

    uint4 pvh[2], pvl[2];
    if (PACKED) {
        pvh[0] = w2hi[(size_t)f0 * 64 + lane];
        pvl[0] = w2lo[(size_t)f0 * 64 + lane];
        pvh[1] = w2hi[(size_t)(f0 + 1) * 64 + lane];
        pvl[1] = w2lo[(size_t)(f0 + 1) * 64 + lane];
    }

    const int nchunk = nfeat / FCHUNK;
    #pragma unroll 1
    for (int ch = 0; ch < nchunk; ++ch) {
        const int fbase = f0 + ch * FCHUNK;

        // ---- stage chunk into LDS (all coalesced float4 global loads) ----
        {
            int r = t >> 2, c4 = (t & 3) << 2;
            float4 xv = *(const float4*)(x + (size_t)(b0 + r) * F_TOTAL + fbase + c4);
            xs[c4 + 0][r] = xv.x; xs[c4 + 1][r] = xv.y;
            xs[c4 + 2][r] = xv.z; xs[c4 + 3][r] = xv.w;
        }
        if (t < 128) {
            int fi = t >> 3, j = (t & 7) << 2;
            *(float4*)&w1s[fi][j] = *(const float4*)(W1 + (size_t)(fbase + fi) * H1 + j);
        } else {
            int t2 = t - 128;
            int fi = t2 >> 3, j = (t2 & 7) << 2;
            *(float4*)&b1s[fi][j] = *(const float4*)(b1 + (size_t)(fbase + fi) * H1 + j);
        }
        if (t < 64) {
            int fi = t >> 2, k = (t & 3) << 2;
            *(float4*)&b2s[fi][k] = *(const float4*)(b2 + (size_t)(fbase + fi) * H2 + k);
        } else if (t < 128) {
            int t2 = t - 64;
            int fi = t2 >> 2, k = (t2 & 3) << 2;
            *(float4*)&w3s[fi][k] = *(const float4*)(W3 + (size_t)(fbase + fi) * H2 + k);
        } else if (t < 128 + FCHUNK) {
            b3s[t - 128] = b3[fbase + (t - 128)];
        }
        __syncthreads();

        #pragma unroll 2
        for (int fi = 0; fi < FCHUNK; ++fi) {
            const int fl = ch * FCHUNK + fi;

            FragU bhi, blo;
            if (PACKED) {
                uint4 vh = pvh[fi & 1], vl = pvl[fi & 1];
                bhi.u[0] = vh.x; bhi.u[1] = vh.y; bhi.u[2] = vh.z; bhi.u[3] = vh.w;
                blo.u[0] = vl.x; blo.u[1] = vl.y; blo.u[2] = vl.z; blo.u[3] = vl.w;
                int fn = (fl + 2 < nfeat) ? fl + 2 : fl;   // prefetch distance 2
                pvh[fi & 1] = w2hi[(size_t)(f0 + fn) * 64 + lane];
                pvl[fi & 1] = w2lo[(size_t)(f0 + fn) * 64 + lane];
            } else {
                float wv[8];
                #pragma unroll
                for (int j = 0; j < 8; ++j)
                    wv[j] = W2[(size_t)(f0 + fl) * (H1 * H2) + (q * 8 + j) * H2 + n];
                split_pack8(wv, bhi.u, blo.u);
            }

            // layer 1 from LDS (broadcast reads)
            const float xm = xs[fi][wave * 16 + n];
            const float4 wa = *(const float4*)&w1s[fi][q * 8];
            const float4 wb = *(const float4*)&w1s[fi][q * 8 + 4];
            const float4 ba = *(const float4*)&b1s[fi][q * 8];
            const float4 bb = *(const float4*)&b1s[fi][q * 8 + 4];
            float h[8];
            h[0] = fmaf(xm, wa.x, ba.x); h[1] = fmaf(xm, wa.y, ba.y);
            h[2] = fmaf(xm, wa.z, ba.z); h[3] = fmaf(xm, wa.w, ba.w);
            h[4] = fmaf(xm, wb.x, bb.x); h[5] = fmaf(xm, wb.y, bb.y);
            h[6] = fmaf(xm, wb.z, bb.z); h[7] = fmaf(xm, wb.w, bb.w);
            #pragma unroll
            for (int j = 0; j < 8; ++j) h[j] = h[j] > 0.f ? h[j] : 0.f;

            FragU ahi, alo;
            split_pack8(h, ahi.u, alo.u);

            floatx4 c = {0.f, 0.f, 0.f, 0.f};
            c = __builtin_amdgcn_mfma_f32_16x16x32_bf16(alo.v, bhi.v, c, 0, 0, 0);
            c = __builtin_amdgcn_mfma_f32_16x16x32_bf16(ahi.v, blo.v, c, 0, 0, 0);
            c = __builtin_amdgcn_mfma_f32_16x16x32_bf16(ahi.v, bhi.v, c, 0, 0, 0);

            const float b2n = b2s[fi][n];
            const float w3n = w3s[fi][n];
            #pragma unroll
            for (int r = 0; r < 4; ++r) {
                float hh = c[r] + b2n;
                hh = hh > 0.f ? hh : 0.f;
                acc[r] = fmaf(hh, w3n, acc[r]);
            }
            accb3 += b3s[fi];
        }
        __syncthreads();
    }

    // Reduce over the 16 columns (n) within each 16-lane group.
    #pragma unroll
    for (int r = 0; r < 4; ++r) {
        float v = acc[r];
        v += __shfl_xor(v, 1);
        v += __shfl_xor(v, 2);
        v += __shfl_xor(v, 4);
        v += __shfl_xor(v, 8);
        acc[r] = v;
    }
    if (n == 0) {
        float4 o;
        o.x = acc[0] + accb3;
        o.y = acc[1] + accb3;
        o.z = acc[2] + accb3;
        o.w = acc[3] + accb3;
        *(float4*)(part + (size_t)blockIdx.y * B_TOTAL + b0 + wave * 16 + q * 4) = o;
    }
}

__global__ __launch_bounds__(256) void nam_finish(
    const float* __restrict__ part, float* __restrict__ out, int ngroups)
{
    const int b = blockIdx.x * 256 + threadIdx.x;
    float s = 0.f;
    for (int g = 0; g < ngroups; ++g) s += part[(size_t)g * B_TOTAL + b];
    out[b] = 1.0f / (1.0f + expf(-s));
}

extern "C" void kernel_launch(void* const* d_in, const int* in_sizes, int n_in,
                              void* d_out, int out_size, void* d_ws, size_t ws_size,
                              hipStream_t stream) {
    const float* x  = (const float*)d_in[0];
    const float* W1 = (const float*)d_in[1];
    const float* b1 = (const float*)d_in[2];
    const float* W2 = (const float*)d_in[3];
    const float* b2 = (const float*)d_in[4];
    const float* W3 = (const float*)d_in[5];
    const float* b3 = (const float*)d_in[6];
    float* out = (float*)d_out;

    const size_t packBytes  = (size_t)F_TOTAL * 64 * 16;            // 256 KB per hi/lo
    const size_t partBytes4 = (size_t)4 * B_TOTAL * sizeof(float);  // 256 KB
    const size_t partBytes1 = (size_t)B_TOTAL * sizeof(float);      // 64 KB

    if (ws_size >= 2 * packBytes + partBytes4) {
        unsigned int* wsHi = (unsigned int*)d_ws;
        unsigned int* wsLo = (unsigned int*)((char*)d_ws + packBytes);
        float* partp = (float*)((char*)d_ws + 2 * packBytes);

        nam_pack<<<F_TOTAL, 64, 0, stream>>>(W2, wsHi, wsLo);
        dim3 grid(B_TOTAL / 64, 4);   // 64 features per block
        nam_main<true><<<grid, 256, 0, stream>>>(
            x, W1, b1, W2, b2, W3, b3,
            (const uint4*)wsHi, (const uint4*)wsLo, partp, F_TOTAL / 4);
        nam_finish<<<B_TOTAL / 256, 256, 0, stream>>>(partp, out, 4);
    } else if (ws_size >= partBytes4) {
        float* partp = (float*)d_ws;
        dim3 grid(B_TOTAL / 64, 4);
        nam_main<false><<<grid, 256, 0, stream>>>(
            x, W1, b1, W2, b2, W3, b3, nullptr, nullptr, partp, F_TOTAL / 4);
        nam_finish<<<B_TOTAL / 256, 256, 0, stream>>>(partp, out, 4);
    } else {
        float* partp = (float*)d_ws;   // needs 64 KB
        dim3 grid(B_TOTAL / 64, 1);
        nam_main<false><<<grid, 256, 0, stream>>>(
            x, W1, b1, W2, b2, W3, b3, nullptr, nullptr, partp, F_TOTAL);
        nam_finish<<<B_TOTAL / 256, 256, 0, stream>>>(partp, out, 1);
    }
}

// Round 5
// 93.464 us; speedup vs baseline: 1.6826x; 1.2156x over previous
//
#include <hip/hip_runtime.h>
#include <math.h>

#define B_TOTAL 16384
#define F_TOTAL 256
#define H1 32
#define H2 16
#define FPB 32     // features per block (ngroups = 8)
#define RPB 128    // rows per block (4 waves x 32 rows)

typedef _Float16 f16;
typedef __attribute__((ext_vector_type(2))) _Float16 f16x2;
typedef __attribute__((ext_vector_type(8))) _Float16 f16x8;
typedef __attribute__((ext_vector_type(4))) float floatx4;

union F8 { uint4 u; f16x2 h2[4]; f16x8 h8; };

// ---------- pack: W2 -> f16 hi/lo B-frags; W1/b1 -> f16 per-q records;
// b2/W3 -> interleaved float2. One block per feature, 64 lanes. ----------
__global__ __launch_bounds__(64) void nam_pack(
    const float* __restrict__ W1, const float* __restrict__ b1,
    const float* __restrict__ W2, const float* __restrict__ b2,
    const float* __restrict__ W3,
    uint4* __restrict__ pkB,      // [F][2][64] uint4: hi frags then lo frags
    uint4* __restrict__ pkW,      // [F][4][2] uint4: {w1 8xf16, b1 8xf16} per q
    float2* __restrict__ pkE)     // [F][16]: {b2, w3} per n
{
    const int f = blockIdx.x;
    const int lane = threadIdx.x;
    const int n = lane & 15, q = lane >> 4;

    // B-frag: lane holds B[k=q*8+j][n], hi = f16 RNE, lo = f16(w - hi)
    F8 H, L;
    #pragma unroll
    for (int j = 0; j < 8; ++j) {
        float w = W2[(size_t)f * (H1 * H2) + (q * 8 + j) * H2 + n];
        f16 hi = (f16)w;
        H.h8[j] = hi;
        L.h8[j] = (f16)(w - (float)hi);
    }
    pkB[(size_t)f * 128 + lane] = H.u;
    pkB[(size_t)f * 128 + 64 + lane] = L.u;

    if (n == 0) {   // one lane per q builds the w1/b1 record
        F8 A, Bb;
        #pragma unroll
        for (int j = 0; j < 8; ++j) {
            A.h8[j]  = (f16)W1[(size_t)f * H1 + q * 8 + j];
            Bb.h8[j] = (f16)b1[(size_t)f * H1 + q * 8 + j];
        }
        pkW[((size_t)f * 4 + q) * 2]     = A.u;
        pkW[((size_t)f * 4 + q) * 2 + 1] = Bb.u;
    }
    if (q == 0) {   // one lane per n builds {b2, w3}
        float2 e;
        e.x = b2[(size_t)f * H2 + n];
        e.y = W3[(size_t)f * H2 + n];
        pkE[(size_t)f * 16 + n] = e;
    }
}

// ---------- main: block = 128 rows x 32 features; wave = 32 rows (2 M16
// tiles sharing B/w1/b1/b2w3). All operands staged to LDS ONCE -> zero
// barriers in the K-loop. B-frags stream from global, depth-2 prefetch.
// Per-feature: layer1 in packed f16, 2x2 chained mfma_f32_16x16x32_f16,
// fp32 epilogue; atomicAdd partial rows into sum[]. ----------
__global__ __launch_bounds__(256, 4) void nam_main(
    const float* __restrict__ x,   // [B, F]
    const float* __restrict__ b3,  // [F]
    const uint4* __restrict__ pkB,
    const uint4* __restrict__ pkW,
    const float2* __restrict__ pkE,
    float* __restrict__ sum)       // [B] pre-zeroed
{
    __shared__ float  xs[FPB][RPB];        // 16 KB, [feat][row]
    __shared__ uint4  w1b1s[FPB * 4 * 2];  // 4 KB
    __shared__ float2 b2w3s[FPB * 16];     // 4 KB
    __shared__ float  b3s[FPB];

    const int t = threadIdx.x;
    const int lane = t & 63;
    const int wave = t >> 6;
    const int n = lane & 15, q = lane >> 4;
    const int b0 = blockIdx.x * RPB;
    const int f0 = blockIdx.y * FPB;

    // ---- one-time staging ----
    {
        int r = t >> 1, c0 = (t & 1) * 16;          // 16 feats per half-row
        const float4* xrow = (const float4*)(x + (size_t)(b0 + r) * F_TOTAL + f0 + c0);
        #pragma unroll
        for (int i = 0; i < 4; ++i) {
            float4 v = xrow[i];
            xs[c0 + i * 4 + 0][r] = v.x; xs[c0 + i * 4 + 1][r] = v.y;
            xs[c0 + i * 4 + 2][r] = v.z; xs[c0 + i * 4 + 3][r] = v.w;
        }
    }
    w1b1s[t] = pkW[(size_t)f0 * 8 + t];                       // 4 KB
    ((uint4*)b2w3s)[t] = ((const uint4*)pkE)[(size_t)f0 * 8 + t];  // 4 KB
    if (t < FPB) b3s[t] = b3[f0 + t];
    __syncthreads();

    const uint4* pB = pkB + (size_t)f0 * 128 + lane;
    uint4 bh[2], bl[2];
    bh[0] = pB[0];   bl[0] = pB[64];
    bh[1] = pB[128]; bl[1] = pB[192];

    floatx4 acc1 = {0.f, 0.f, 0.f, 0.f};
    floatx4 acc2 = {0.f, 0.f, 0.f, 0.f};
    const int rb = wave * 32;
    const f16x2 z2 = {(f16)0, (f16)0};

    #pragma unroll 2
    for (int fi = 0; fi < FPB; ++fi) {
        F8 Bh, Bl;
        Bh.u = bh[fi & 1];
        Bl.u = bl[fi & 1];
        int nf = (fi + 2 < FPB) ? fi + 2 : fi;   // clamped prefetch
        bh[fi & 1] = pB[(size_t)nf * 128];
        bl[fi & 1] = pB[(size_t)nf * 128 + 64];

        const float xm1 = xs[fi][rb + n];
        const float xm2 = xs[fi][rb + 16 + n];
        F8 W, Bi;
        W.u  = w1b1s[(fi * 4 + q) * 2];
        Bi.u = w1b1s[(fi * 4 + q) * 2 + 1];

        const f16 xh1 = (f16)xm1;           // v_cvt_f16_f32 (RNE)
        const f16 xh2 = (f16)xm2;
        const f16x2 x1 = {xh1, xh1};
        const f16x2 x2 = {xh2, xh2};

        F8 A1, A2;
        #pragma unroll
        for (int tt = 0; tt < 4; ++tt) {
            f16x2 h1 = x1 * W.h2[tt] + Bi.h2[tt];   // v_pk_fma_f16
            f16x2 h2 = x2 * W.h2[tt] + Bi.h2[tt];
            A1.h2[tt] = __builtin_elementwise_max(h1, z2);  // v_pk_max_f16
            A2.h2[tt] = __builtin_elementwise_max(h2, z2);
        }

        floatx4 c1 = {0.f, 0.f, 0.f, 0.f};
        floatx4 c2 = {0.f, 0.f, 0.f, 0.f};
        c1 = __builtin_amdgcn_mfma_f32_16x16x32_f16(A1.h8, Bh.h8, c1, 0, 0, 0);
        c1 = __builtin_amdgcn_mfma_f32_16x16x32_f16(A1.h8, Bl.h8, c1, 0, 0, 0);
        c2 = __builtin_amdgcn_mfma_f32_16x16x32_f16(A2.h8, Bh.h8, c2, 0, 0, 0);
        c2 = __builtin_amdgcn_mfma_f32_16x16x32_f16(A2.h8, Bl.h8, c2, 0, 0, 0);

        const float2 bw = b2w3s[fi * 16 + n];       // one ds_read_b64
        #pragma unroll
        for (int r = 0; r < 4; ++r) {
            float u1 = c1[r] + bw.x; u1 = u1 > 0.f ? u1 : 0.f;
            acc1[r] = fmaf(u1, bw.y, acc1[r]);
            float u2 = c2[r] + bw.x; u2 = u2 > 0.f ? u2 : 0.f;
            acc2[r] = fmaf(u2, bw.y, acc2[r]);
        }
    }

    float accb3 = 0.f;
    #pragma unroll
    for (int i = 0; i < FPB; ++i) accb3 += b3s[i];

    #pragma unroll
    for (int r = 0; r < 4; ++r) {
        float v1 = acc1[r], v2 = acc2[r];
        v1 += __shfl_xor(v1, 1); v2 += __shfl_xor(v2, 1);
        v1 += __shfl_xor(v1, 2); v2 += __shfl_xor(v2, 2);
        v1 += __shfl_xor(v1, 4); v2 += __shfl_xor(v2, 4);
        v1 += __shfl_xor(v1, 8); v2 += __shfl_xor(v2, 8);
        acc1[r] = v1; acc2[r] = v2;
    }
    if (n == 0) {
        const int base = b0 + rb + q * 4;
        #pragma unroll
        for (int r = 0; r < 4; ++r) {
            atomicAdd(&sum[base + r],      acc1[r] + accb3);
            atomicAdd(&sum[base + 16 + r], acc2[r] + accb3);
        }
    }
}

__global__ __launch_bounds__(256) void nam_sigmoid(
    const float* __restrict__ sum, float* __restrict__ out)
{
    const int b = blockIdx.x * 256 + threadIdx.x;
    out[b] = 1.0f / (1.0f + expf(-sum[b]));
}

extern "C" void kernel_launch(void* const* d_in, const int* in_sizes, int n_in,
                              void* d_out, int out_size, void* d_ws, size_t ws_size,
                              hipStream_t stream) {
    const float* x  = (const float*)d_in[0];
    const float* W1 = (const float*)d_in[1];
    const float* b1 = (const float*)d_in[2];
    const float* W2 = (const float*)d_in[3];
    const float* b2 = (const float*)d_in[4];
    const float* W3 = (const float*)d_in[5];
    const float* b3 = (const float*)d_in[6];
    float* out = (float*)d_out;

    // ws layout (640 KB total; ws_size >= 768 KB proven in rounds 2/3):
    //   [0, 512K)     pkB   f16 hi/lo B-frags
    //   [512K, 544K)  pkW   f16 w1/b1 records
    //   [544K, 576K)  pkE   {b2, w3} float2
    //   [576K, 640K)  sum   [B] fp32
    char* ws = (char*)d_ws;
    uint4*  pkB = (uint4*)ws;
    uint4*  pkW = (uint4*)(ws + (512 << 10));
    float2* pkE = (float2*)(ws + (544 << 10));
    float*  sum = (float*)(ws + (576 << 10));

    nam_pack<<<F_TOTAL, 64, 0, stream>>>(W1, b1, W2, b2, W3, pkB, pkW, pkE);
    (void)hipMemsetAsync(sum, 0, B_TOTAL * sizeof(float), stream);

    dim3 grid(B_TOTAL / RPB, F_TOTAL / FPB);   // (128, 8)
    nam_main<<<grid, 256, 0, stream>>>(x, b3, pkB, pkW, pkE, sum);

    nam_sigmoid<<<B_TOTAL / 256, 256, 0, stream>>>(sum, out);
}

// Round 7
// 91.983 us; speedup vs baseline: 1.7097x; 1.0161x over previous
//
#include <hip/hip_runtime.h>
#include <math.h>

#define B_TOTAL 16384
#define F_TOTAL 256
#define H1 32
#define H2 16
#define FPB 32     // features per block (ngroups = 8)
#define RPB 128    // rows per block (4 waves x 32 rows)

typedef _Float16 f16;
typedef __attribute__((ext_vector_type(2))) _Float16 f16x2;
typedef __attribute__((ext_vector_type(8))) _Float16 f16x8;
typedef __attribute__((ext_vector_type(4))) float floatx4;

union F8 { uint4 u; f16x2 h2[4]; f16x8 h8; };

// ---------- pack: W2 -> f16 hi/lo B-frags; W1/b1 -> f16 per-q records;
// b2/W3 -> interleaved float2. One block per feature, 64 lanes. ----------
__global__ __launch_bounds__(64) void nam_pack(
    const float* __restrict__ W1, const float* __restrict__ b1,
    const float* __restrict__ W2, const float* __restrict__ b2,
    const float* __restrict__ W3,
    uint4* __restrict__ pkB,      // [F][2][64] uint4: hi frags then lo frags
    uint4* __restrict__ pkW,      // [F][4][2] uint4: {w1 8xf16, b1 8xf16} per q
    float2* __restrict__ pkE)     // [F][16]: {b2, w3} per n
{
    const int f = blockIdx.x;
    const int lane = threadIdx.x;
    const int n = lane & 15, q = lane >> 4;

    // B-frag: lane holds B[k=q*8+j][n], hi = f16 RNE, lo = f16(w - hi)
    F8 H, L;
    #pragma unroll
    for (int j = 0; j < 8; ++j) {
        float w = W2[(size_t)f * (H1 * H2) + (q * 8 + j) * H2 + n];
        f16 hi = (f16)w;
        H.h8[j] = hi;
        L.h8[j] = (f16)(w - (float)hi);
    }
    pkB[(size_t)f * 128 + lane] = H.u;
    pkB[(size_t)f * 128 + 64 + lane] = L.u;

    if (n == 0) {   // one lane per q builds the w1/b1 record
        F8 A, Bb;
        #pragma unroll
        for (int j = 0; j < 8; ++j) {
            A.h8[j]  = (f16)W1[(size_t)f * H1 + q * 8 + j];
            Bb.h8[j] = (f16)b1[(size_t)f * H1 + q * 8 + j];
        }
        pkW[((size_t)f * 4 + q) * 2]     = A.u;
        pkW[((size_t)f * 4 + q) * 2 + 1] = Bb.u;
    }
    if (q == 0) {   // one lane per n builds {b2, w3}
        float2 e;
        e.x = b2[(size_t)f * H2 + n];
        e.y = W3[(size_t)f * H2 + n];
        pkE[(size_t)f * 16 + n] = e;
    }
}

// ---------- main: block = 128 rows x 32 features; wave = 32 rows (2 M16
// tiles sharing B/w1/b1/b2w3). All operands staged to LDS ONCE -> zero
// barriers in the K-loop. B-frags stream from global, depth-2 prefetch.
// Per-feature: layer1 in packed f16, 2x2 chained mfma_f32_16x16x32_f16,
// fp32 epilogue. Partials stored directly to part[group][B] (no atomics,
// no memset). Math path byte-identical to the round-5 passing kernel. ----------
__global__ __launch_bounds__(256, 4) void nam_main(
    const float* __restrict__ x,   // [B, F]
    const float* __restrict__ b3,  // [F]
    const uint4* __restrict__ pkB,
    const uint4* __restrict__ pkW,
    const float2* __restrict__ pkE,
    float* __restrict__ part)      // [8][B], fully overwritten
{
    __shared__ float  xs[FPB][RPB];        // 16 KB, [feat][row]
    __shared__ uint4  w1b1s[FPB * 4 * 2];  // 4 KB
    __shared__ float2 b2w3s[FPB * 16];     // 4 KB
    __shared__ float  b3s[FPB];

    const int t = threadIdx.x;
    const int lane = t & 63;
    const int wave = t >> 6;
    const int n = lane & 15, q = lane >> 4;
    const int b0 = blockIdx.x * RPB;
    const int f0 = blockIdx.y * FPB;

    // ---- one-time staging ----
    {
        int r = t >> 1, c0 = (t & 1) * 16;          // 16 feats per half-row
        const float4* xrow = (const float4*)(x + (size_t)(b0 + r) * F_TOTAL + f0 + c0);
        #pragma unroll
        for (int i = 0; i < 4; ++i) {
            float4 v = xrow[i];
            xs[c0 + i * 4 + 0][r] = v.x; xs[c0 + i * 4 + 1][r] = v.y;
            xs[c0 + i * 4 + 2][r] = v.z; xs[c0 + i * 4 + 3][r] = v.w;
        }
    }
    w1b1s[t] = pkW[(size_t)f0 * 8 + t];                       // 4 KB
    ((uint4*)b2w3s)[t] = ((const uint4*)pkE)[(size_t)f0 * 8 + t];  // 4 KB
    if (t < FPB) b3s[t] = b3[f0 + t];
    __syncthreads();

    const uint4* pB = pkB + (size_t)f0 * 128 + lane;
    uint4 bh[2], bl[2];
    bh[0] = pB[0];   bl[0] = pB[64];
    bh[1] = pB[128]; bl[1] = pB[192];

    floatx4 acc1 = {0.f, 0.f, 0.f, 0.f};
    floatx4 acc2 = {0.f, 0.f, 0.f, 0.f};
    const int rb = wave * 32;
    const f16x2 z2 = {(f16)0, (f16)0};

    #pragma unroll 2
    for (int fi = 0; fi < FPB; ++fi) {
        F8 Bh, Bl;
        Bh.u = bh[fi & 1];
        Bl.u = bl[fi & 1];
        int nf = (fi + 2 < FPB) ? fi + 2 : fi;   // clamped prefetch
        bh[fi & 1] = pB[(size_t)nf * 128];
        bl[fi & 1] = pB[(size_t)nf * 128 + 64];

        const float xm1 = xs[fi][rb + n];
        const float xm2 = xs[fi][rb + 16 + n];
        F8 W, Bi;
        W.u  = w1b1s[(fi * 4 + q) * 2];
        Bi.u = w1b1s[(fi * 4 + q) * 2 + 1];

        const f16 xh1 = (f16)xm1;           // v_cvt_f16_f32 (RNE)
        const f16 xh2 = (f16)xm2;
        const f16x2 x1 = {xh1, xh1};
        const f16x2 x2 = {xh2, xh2};

        F8 A1, A2;
        #pragma unroll
        for (int tt = 0; tt < 4; ++tt) {
            f16x2 h1 = x1 * W.h2[tt] + Bi.h2[tt];   // v_pk_fma_f16
            f16x2 h2 = x2 * W.h2[tt] + Bi.h2[tt];
            A1.h2[tt] = __builtin_elementwise_max(h1, z2);  // v_pk_max_f16
            A2.h2[tt] = __builtin_elementwise_max(h2, z2);
        }

        floatx4 c1 = {0.f, 0.f, 0.f, 0.f};
        floatx4 c2 = {0.f, 0.f, 0.f, 0.f};
        c1 = __builtin_amdgcn_mfma_f32_16x16x32_f16(A1.h8, Bh.h8, c1, 0, 0, 0);
        c1 = __builtin_amdgcn_mfma_f32_16x16x32_f16(A1.h8, Bl.h8, c1, 0, 0, 0);
        c2 = __builtin_amdgcn_mfma_f32_16x16x32_f16(A2.h8, Bh.h8, c2, 0, 0, 0);
        c2 = __builtin_amdgcn_mfma_f32_16x16x32_f16(A2.h8, Bl.h8, c2, 0, 0, 0);

        const float2 bw = b2w3s[fi * 16 + n];       // one ds_read_b64
        #pragma unroll
        for (int r = 0; r < 4; ++r) {
            float u1 = c1[r] + bw.x; u1 = u1 > 0.f ? u1 : 0.f;
            acc1[r] = fmaf(u1, bw.y, acc1[r]);
            float u2 = c2[r] + bw.x; u2 = u2 > 0.f ? u2 : 0.f;
            acc2[r] = fmaf(u2, bw.y, acc2[r]);
        }
    }

    float accb3 = 0.f;
    #pragma unroll
    for (int i = 0; i < FPB; ++i) accb3 += b3s[i];

    #pragma unroll
    for (int r = 0; r < 4; ++r) {
        float v1 = acc1[r], v2 = acc2[r];
        v1 += __shfl_xor(v1, 1); v2 += __shfl_xor(v2, 1);
        v1 += __shfl_xor(v1, 2); v2 += __shfl_xor(v2, 2);
        v1 += __shfl_xor(v1, 4); v2 += __shfl_xor(v2, 4);
        v1 += __shfl_xor(v1, 8); v2 += __shfl_xor(v2, 8);
        acc1[r] = v1; acc2[r] = v2;
    }
    if (n == 0) {
        // wave covers rows b0+rb .. b0+rb+31; lane (q, n=0) writes rows q*4..q*4+3
        float* dst = part + (size_t)blockIdx.y * B_TOTAL + b0 + rb;
        float4 o1, o2;
        o1.x = acc1[0] + accb3; o1.y = acc1[1] + accb3;
        o1.z = acc1[2] + accb3; o1.w = acc1[3] + accb3;
        o2.x = acc2[0] + accb3; o2.y = acc2[1] + accb3;
        o2.z = acc2[2] + accb3; o2.w = acc2[3] + accb3;
        *(float4*)(dst + q * 4)      = o1;
        *(float4*)(dst + 16 + q * 4) = o2;
    }
}

__global__ __launch_bounds__(256) void nam_finish(
    const float* __restrict__ part, float* __restrict__ out)
{
    const int b = blockIdx.x * 256 + threadIdx.x;
    float s = 0.f;
    #pragma unroll
    for (int g = 0; g < 8; ++g) s += part[(size_t)g * B_TOTAL + b];
    out[b] = 1.0f / (1.0f + expf(-s));
}

extern "C" void kernel_launch(void* const* d_in, const int* in_sizes, int n_in,
                              void* d_out, int out_size, void* d_ws, size_t ws_size,
                              hipStream_t stream) {
    const float* x  = (const float*)d_in[0];
    const float* W1 = (const float*)d_in[1];
    const float* b1 = (const float*)d_in[2];
    const float* W2 = (const float*)d_in[3];
    const float* b2 = (const float*)d_in[4];
    const float* W3 = (const float*)d_in[5];
    const float* b3 = (const float*)d_in[6];
    float* out = (float*)d_out;

    // ws layout (1088 KB total; ws is ~268 MB per harness poison fills):
    //   [0, 512K)      pkB   f16 hi/lo B-frags
    //   [512K, 544K)   pkW   f16 w1/b1 records
    //   [544K, 576K)   pkE   {b2, w3} float2
    //   [576K, 1088K)  part  [8][B] fp32 partials (every slot stored each launch)
    char* ws = (char*)d_ws;
    uint4*  pkB   = (uint4*)ws;
    uint4*  pkW   = (uint4*)(ws + (512 << 10));
    float2* pkE   = (float2*)(ws + (544 << 10));
    float*  partp = (float*)(ws + (576 << 10));

    nam_pack<<<F_TOTAL, 64, 0, stream>>>(W1, b1, W2, b2, W3, pkB, pkW, pkE);

    dim3 grid(B_TOTAL / RPB, F_TOTAL / FPB);   // (128, 8)
    nam_main<<<grid, 256, 0, stream>>>(x, b3, pkB, pkW, pkE, partp);

    nam_finish<<<B_TOTAL / 256, 256, 0, stream>>>(partp, out);
}